// Round 2
// baseline (2356.907 us; speedup 1.0000x reference)
//
#include <hip/hip_runtime.h>

constexpr int NE = 8192;
constexpr int ED = 256;
constexpr int BS = 32768;

constexpr int BM = 64;     // rows per block
constexpr int BN = 64;     // cols per tile step
constexpr int BK = 32;     // k per stage
constexpr int TM = 8;      // rows per tile-thread
constexpr int TN = 8;      // cols per tile-thread
constexpr int NTH = 256;
constexpr int LDT = BM + 4;   // LDS row stride (68 words, keeps 16B align)

// ---------- e2[n] = ||e_n||^2 (accuracy non-critical: e2 < ulp(z2)/2 always) ----------
__global__ void e2_kernel(const float* __restrict__ e, float* __restrict__ e2) {
    int row  = blockIdx.x * 4 + (threadIdx.x >> 6);
    int lane = threadIdx.x & 63;
    float4 v = reinterpret_cast<const float4*>(e + (size_t)row * ED)[lane];
    float s = v.x * v.x + v.y * v.y + v.z * v.z + v.w * v.w;
#pragma unroll
    for (int off = 32; off > 0; off >>= 1) s += __shfl_down(s, off);
    if (lane == 0) e2[row] = s;
}

// ---------- z2[b]: replicate numpy pairwise fp32 sum of fl(z*z), n=256 ----------
// pairwise(256) = P(a[0:128]) + P(a[128:256]);  P(128): 8 accumulators r_j = sum_t a[8t+j]
// (sequential t), combined ((r0+r1)+(r2+r3))+((r4+r5)+(r6+r7)).
__global__ void z2_kernel(const float* __restrict__ z, float* __restrict__ z2) {
    int gtid = blockIdx.x * blockDim.x + threadIdx.x;
    int wave = gtid >> 6;
    int lane = threadIdx.x & 63;
    int sub  = lane & 7;          // accumulator index j
    int rloc = lane >> 3;         // row within wave (0..7)
    int row  = wave * 8 + rloc;
    const float* a = z + (size_t)row * ED;

    float b0 = 0.f, b1 = 0.f;
#pragma unroll
    for (int t = 0; t < 16; ++t) {
        float v = a[8 * t + sub];
        b0 = __fadd_rn(b0, __fmul_rn(v, v));
    }
#pragma unroll
    for (int t = 0; t < 16; ++t) {
        float v = a[128 + 8 * t + sub];
        b1 = __fadd_rn(b1, __fmul_rn(v, v));
    }
    // combine tree over the 8 sub-lanes (RN add is bitwise commutative, so every
    // lane of a pair computes identical bits)
    b0 = __fadd_rn(b0, __shfl_xor(b0, 1));
    b0 = __fadd_rn(b0, __shfl_xor(b0, 2));
    b0 = __fadd_rn(b0, __shfl_xor(b0, 4));
    b1 = __fadd_rn(b1, __shfl_xor(b1, 1));
    b1 = __fadd_rn(b1, __shfl_xor(b1, 2));
    b1 = __fadd_rn(b1, __shfl_xor(b1, 4));
    float tot = __fadd_rn(b0, b1);
    if (sub == 0) z2[row] = tot;
}

// ---------- fused distance + argmin + gather, numpy-einsum bit replication ----------
// dot_np = (A0+A1)+(A2+A3), A_j = sequential fp32 sum over t of fl(z[4t+j]*e[4t+j])
// (SSE3 einsum: 4 lanes, separate mul/add roundings, hadd combine).
__global__ __launch_bounds__(NTH, 2) void vq_kernel(
        const float* __restrict__ z, const float* __restrict__ e,
        const float* __restrict__ z2, const float* __restrict__ e2,
        float* __restrict__ out) {
    __shared__ __align__(16) float zs[BK][LDT];   // zs[k][row]
    __shared__ __align__(16) float es[BK][LDT];   // es[k][col]
    __shared__ float e2s[BN];
    __shared__ int   best_s[BM];

    const int tid = threadIdx.x;
    const int kl  = tid & 3;        // k-lane: handles k ≡ kl (mod 4)
    const int tt  = tid >> 2;       // tile-thread 0..63
    const int ttx = tt & 7;         // col group
    const int tty = tt >> 3;        // row group
    const int row0 = blockIdx.x * BM;

    float z2r[TM];
#pragma unroll
    for (int i = 0; i < TM; ++i) z2r[i] = z2[row0 + tty * TM + i];

    float run_min[TM];
    int   run_idx[TM];
#pragma unroll
    for (int i = 0; i < TM; ++i) { run_min[i] = 3.4e38f; run_idx[i] = 0; }

    for (int nt = 0; nt < NE / BN; ++nt) {
        const int c0 = nt * BN;
        float acc[TM][TN];
#pragma unroll
        for (int i = 0; i < TM; ++i)
#pragma unroll
            for (int j = 0; j < TN; ++j) acc[i][j] = 0.f;

        __syncthreads();                        // prev-iter readers done
        if (tid < BN) e2s[tid] = e2[c0 + tid];

        for (int ks = 0; ks < ED / BK; ++ks) {
            const int k0 = ks * BK;
            if (ks) __syncthreads();
#pragma unroll
            for (int i = 0; i < 2; ++i) {       // stage both tiles, transposed
                int f4 = tid + i * NTH;         // 0..511
                int r  = f4 >> 3;               // 0..63
                int kq = f4 & 7;
                float4 v = *reinterpret_cast<const float4*>(
                    z + (size_t)(row0 + r) * ED + k0 + kq * 4);
                zs[kq * 4 + 0][r] = v.x; zs[kq * 4 + 1][r] = v.y;
                zs[kq * 4 + 2][r] = v.z; zs[kq * 4 + 3][r] = v.w;
                float4 w = *reinterpret_cast<const float4*>(
                    e + (size_t)(c0 + r) * ED + k0 + kq * 4);
                es[kq * 4 + 0][r] = w.x; es[kq * 4 + 1][r] = w.y;
                es[kq * 4 + 2][r] = w.z; es[kq * 4 + 3][r] = w.w;
            }
            __syncthreads();
#pragma unroll
            for (int t = 0; t < BK / 4; ++t) {
                const int kk = t * 4 + kl;      // this thread's k (mod-4 lane)
                float4 a0 = *reinterpret_cast<const float4*>(&zs[kk][tty * TM]);
                float4 a1 = *reinterpret_cast<const float4*>(&zs[kk][tty * TM + 4]);
                float4 c0v = *reinterpret_cast<const float4*>(&es[kk][ttx * TN]);
                float4 c1v = *reinterpret_cast<const float4*>(&es[kk][ttx * TN + 4]);
                float a[TM] = {a0.x, a0.y, a0.z, a0.w, a1.x, a1.y, a1.z, a1.w};
                float b[TN] = {c0v.x, c0v.y, c0v.z, c0v.w, c1v.x, c1v.y, c1v.z, c1v.w};
#pragma unroll
                for (int i = 0; i < TM; ++i)
#pragma unroll
                    for (int j = 0; j < TN; ++j)
                        acc[i][j] = __fadd_rn(acc[i][j], __fmul_rn(a[i], b[j]));
            }
        }

        // combine the 4 k-lane partials: (A0+A1)+(A2+A3), then quantized distance
#pragma unroll
        for (int i = 0; i < TM; ++i) {
#pragma unroll
            for (int j = 0; j < TN; ++j) {
                float s = __fadd_rn(acc[i][j], __shfl_xor(acc[i][j], 1));
                s = __fadd_rn(s, __shfl_xor(s, 2));   // all 4 k-lanes: identical bits
                float t1 = __fadd_rn(z2r[i], e2s[ttx * TN + j]);
                float d  = __fsub_rn(t1, __fmul_rn(2.0f, s));
                int   c  = c0 + ttx * TN + j;
                if (d < run_min[i]) { run_min[i] = d; run_idx[i] = c; }
            }
        }
    }

    // reduce (min, first-idx) across the 32-lane tty group (8 ttx × 4 redundant kl)
#pragma unroll
    for (int i = 0; i < TM; ++i) {
        float m  = run_min[i];
        int   id = run_idx[i];
#pragma unroll
        for (int off = 16; off > 0; off >>= 1) {
            float om  = __shfl_down(m, off);
            int   oid = __shfl_down(id, off);
            if (om < m || (om == m && oid < id)) { m = om; id = oid; }
        }
        if ((tid & 31) == 0) best_s[tty * TM + i] = id;
    }
    __syncthreads();

    float* zq   = out;
    float* idxf = out + (size_t)BS * ED;
    if (tid < BM) idxf[row0 + tid] = (float)best_s[tid];
    for (int w = tid; w < BM * (ED / 4); w += NTH) {
        int r  = w >> 6;
        int q  = w & 63;
        int bi = best_s[r];
        float4 v = *reinterpret_cast<const float4*>(e + (size_t)bi * ED + q * 4);
        *reinterpret_cast<float4*>(zq + (size_t)(row0 + r) * ED + q * 4) = v;
    }
}

extern "C" void kernel_launch(void* const* d_in, const int* in_sizes, int n_in,
                              void* d_out, int out_size, void* d_ws, size_t ws_size,
                              hipStream_t stream) {
    const float* z = (const float*)d_in[0];
    const float* e = (const float*)d_in[1];
    float* out = (float*)d_out;
    float* e2  = (float*)d_ws;          // 8192 floats
    float* z2  = e2 + NE;               // 32768 floats

    hipLaunchKernelGGL(e2_kernel, dim3(NE / 4), dim3(256), 0, stream, e, e2);
    hipLaunchKernelGGL(z2_kernel, dim3(BS / 32), dim3(256), 0, stream, z, z2);
    hipLaunchKernelGGL(vq_kernel, dim3(BS / BM), dim3(NTH), 0, stream,
                       z, e, z2, e2, out);
}

// Round 3
// 1447.885 us; speedup vs baseline: 1.6278x; 1.6278x over previous
//
#include <hip/hip_runtime.h>

constexpr int NE = 8192;
constexpr int ED = 256;
constexpr int BS = 32768;
constexpr float DELTA = 4e-4f;   // worst-case |d_bf16 - d_np| bound (row-shift removed) x safety

typedef short bf16x8 __attribute__((ext_vector_type(8)));
typedef float f32x4 __attribute__((ext_vector_type(4)));

__device__ __forceinline__ short f2bf(float f) {            // RNE f32 -> bf16
    unsigned u = __float_as_uint(f);
    u = u + 0x7FFFu + ((u >> 16) & 1u);
    return (short)(u >> 16);
}

// ---------- np-exact pairwise ||row||^2 (verified bit-exact vs np.sum in R2) ----------
// pairwise(256) = P(0:128) + P(128:256); P(128): 8 accs r_j = seq-sum a[8t+j],
// combined ((r0+r1)+(r2+r3))+((r4+r5)+(r6+r7)).
__global__ void sq_np_kernel(const float* __restrict__ a, float* __restrict__ out) {
    int gtid = blockIdx.x * blockDim.x + threadIdx.x;
    int wave = gtid >> 6;
    int lane = threadIdx.x & 63;
    int sub  = lane & 7;
    int row  = wave * 8 + (lane >> 3);
    const float* p = a + (size_t)row * ED;
    float b0 = 0.f, b1 = 0.f;
#pragma unroll
    for (int t = 0; t < 16; ++t) { float v = p[8 * t + sub];       b0 = __fadd_rn(b0, __fmul_rn(v, v)); }
#pragma unroll
    for (int t = 0; t < 16; ++t) { float v = p[128 + 8 * t + sub]; b1 = __fadd_rn(b1, __fmul_rn(v, v)); }
    b0 = __fadd_rn(b0, __shfl_xor(b0, 1));
    b0 = __fadd_rn(b0, __shfl_xor(b0, 2));
    b0 = __fadd_rn(b0, __shfl_xor(b0, 4));
    b1 = __fadd_rn(b1, __shfl_xor(b1, 1));
    b1 = __fadd_rn(b1, __shfl_xor(b1, 2));
    b1 = __fadd_rn(b1, __shfl_xor(b1, 4));
    if (sub == 0) out[row] = __fadd_rn(b0, b1);
}

// ---------- pass 1: bf16 MFMA GEMM, per-(row, 64-col-chunk) min of d' = e2 - 2*dot ----------
// 128x128 tile, K=256 in 4 steps of 64. 4 waves = 2x2 quadrants of 64x64.
// LDS: A/B tiles bf16 [128 rows][64 k], 16B-unit XOR swizzle (byte ^= (row&7)<<4).
__global__ __launch_bounds__(256) void vq_pass1(
        const float* __restrict__ z, const float* __restrict__ e,
        const float* __restrict__ e2, float* __restrict__ wsmin) {
    __shared__ __align__(16) char smem[32768];
    char* As = smem;
    char* Bs = smem + 16384;

    const int tid  = threadIdx.x;
    const int bm   = blockIdx.x & 255;   // m fastest: consecutive blocks share B-tile (L2)
    const int bn   = blockIdx.x >> 8;
    const int row0 = bm * 128;
    const int col0 = bn * 128;

    const int wid  = tid >> 6, lane = tid & 63;
    const int wr   = (wid >> 1) * 64, wc = (wid & 1) * 64;
    const int lr   = lane & 15;          // M/N offset within fragment
    const int lk   = lane >> 4;          // k-subgroup (8 bf16 each)
    const int sw   = (lr & 7) << 4;      // read-side swizzle ((row&7)<<4)

    f32x4 acc[4][4];
#pragma unroll
    for (int i = 0; i < 4; ++i)
#pragma unroll
        for (int j = 0; j < 4; ++j) acc[i][j] = (f32x4){0.f, 0.f, 0.f, 0.f};

    for (int kstep = 0; kstep < 4; ++kstep) {
        const int k0 = kstep * 64;
        if (kstep) __syncthreads();      // readers of previous tile done
#pragma unroll
        for (int it = 0; it < 4; ++it) { // stage A and B tiles (f32 -> bf16 cvt)
            int idx = tid + it * 256;    // 0..1023 = 128 rows x 8 k-units
            int m = idx >> 3, ku = idx & 7;
            const float4* sa = reinterpret_cast<const float4*>(
                z + (size_t)(row0 + m) * ED + k0 + ku * 8);
            float4 a0 = sa[0], a1 = sa[1];
            bf16x8 ha;
            ha[0] = f2bf(a0.x); ha[1] = f2bf(a0.y); ha[2] = f2bf(a0.z); ha[3] = f2bf(a0.w);
            ha[4] = f2bf(a1.x); ha[5] = f2bf(a1.y); ha[6] = f2bf(a1.z); ha[7] = f2bf(a1.w);
            *reinterpret_cast<bf16x8*>(As + m * 128 + ((ku * 16) ^ ((m & 7) << 4))) = ha;
            const float4* sb = reinterpret_cast<const float4*>(
                e + (size_t)(col0 + m) * ED + k0 + ku * 8);
            float4 b0 = sb[0], b1 = sb[1];
            bf16x8 hb;
            hb[0] = f2bf(b0.x); hb[1] = f2bf(b0.y); hb[2] = f2bf(b0.z); hb[3] = f2bf(b0.w);
            hb[4] = f2bf(b1.x); hb[5] = f2bf(b1.y); hb[6] = f2bf(b1.z); hb[7] = f2bf(b1.w);
            *reinterpret_cast<bf16x8*>(Bs + m * 128 + ((ku * 16) ^ ((m & 7) << 4))) = hb;
        }
        __syncthreads();
#pragma unroll
        for (int ks = 0; ks < 2; ++ks) { // two k=32 subtiles
            bf16x8 af[4], bg[4];
#pragma unroll
            for (int i = 0; i < 4; ++i) {
                int mrow = wr + i * 16 + lr;
                af[i] = *reinterpret_cast<const bf16x8*>(
                    As + mrow * 128 + (((ks * 4 + lk) * 16) ^ sw));
                int ncol = wc + i * 16 + lr;
                bg[i] = *reinterpret_cast<const bf16x8*>(
                    Bs + ncol * 128 + (((ks * 4 + lk) * 16) ^ sw));
            }
#pragma unroll
            for (int i = 0; i < 4; ++i)
#pragma unroll
                for (int j = 0; j < 4; ++j)
                    acc[i][j] = __builtin_amdgcn_mfma_f32_16x16x32_bf16(
                        af[i], bg[j], acc[i][j], 0, 0, 0);
        }
    }

    // epilogue: d' = e2[col] - 2*acc ; per-row min over the wave's 64 cols
    float e2v[4];
#pragma unroll
    for (int j = 0; j < 4; ++j) e2v[j] = e2[col0 + wc + j * 16 + lr];
    const int chunk = (col0 + wc) >> 6;
#pragma unroll
    for (int i = 0; i < 4; ++i) {
#pragma unroll
        for (int q = 0; q < 4; ++q) {
            float m0 = fminf(fminf(e2v[0] - 2.f * acc[i][0][q],
                                   e2v[1] - 2.f * acc[i][1][q]),
                             fminf(e2v[2] - 2.f * acc[i][2][q],
                                   e2v[3] - 2.f * acc[i][3][q]));
#pragma unroll
            for (int off = 1; off < 16; off <<= 1)
                m0 = fminf(m0, __shfl_xor(m0, off));
            if (lr == 0) {
                int row = row0 + wr + i * 16 + lk * 4 + q;   // C/D: row=(lane>>4)*4+reg
                wsmin[(size_t)row * 128 + chunk] = m0;
            }
        }
    }
}

// ---------- pass 2: exact np re-evaluation of selected chunks + argmin + gather ----------
__global__ __launch_bounds__(256) void vq_pass2(
        const float* __restrict__ z, const float* __restrict__ e,
        const float* __restrict__ z2, const float* __restrict__ e2,
        const float* __restrict__ wsmin, float* __restrict__ out) {
    __shared__ float zrow[4][ED];
    const int wid = threadIdx.x >> 6, lane = threadIdx.x & 63;
    const int r = blockIdx.x * 4 + wid;
    const int kl = lane & 3, slot = lane >> 2;

    *reinterpret_cast<float4*>(&zrow[wid][lane * 4]) =
        *reinterpret_cast<const float4*>(z + (size_t)r * ED + lane * 4);
    __syncthreads();

    const float z2r = z2[r];
    float ca = wsmin[(size_t)r * 128 + lane];
    float cb = wsmin[(size_t)r * 128 + 64 + lane];
    float rmn = fminf(ca, cb);
#pragma unroll
    for (int off = 1; off < 64; off <<= 1) rmn = fminf(rmn, __shfl_xor(rmn, off));
    const float thr = rmn + DELTA;

    float bd = 3.4e38f;
    int   bc = NE;
    for (int ch = 0; ch < 128; ++ch) {
        float v1 = __shfl(ca, ch & 63);
        float v2 = __shfl(cb, ch & 63);
        float cv = (ch < 64) ? v1 : v2;
        if (cv <= thr) {
#pragma unroll 1
            for (int r4 = 0; r4 < 4; ++r4) {
                int col = ch * 64 + r4 * 16 + slot;
                const float* ec = e + (size_t)col * ED;
                float a0 = 0.f;
#pragma unroll
                for (int t = 0; t < 64; ++t)          // strict sequential SSE lane sum
                    a0 = __fadd_rn(a0, __fmul_rn(zrow[wid][4 * t + kl], ec[4 * t + kl]));
                float s = __fadd_rn(a0, __shfl_xor(a0, 1));
                s = __fadd_rn(s, __shfl_xor(s, 2));   // (A0+A1)+(A2+A3), all 4 kl identical
                float d = __fsub_rn(__fadd_rn(z2r, e2[col]), __fmul_rn(2.0f, s));
                if (d < bd || (d == bd && col < bc)) { bd = d; bc = col; }
            }
        }
    }
#pragma unroll
    for (int off = 1; off < 64; off <<= 1) {
        float od = __shfl_xor(bd, off);
        int   oc = __shfl_xor(bc, off);
        if (od < bd || (od == bd && oc < bc)) { bd = od; bc = oc; }
    }
    if (lane == 0) out[(size_t)BS * ED + r] = (float)bc;
    *reinterpret_cast<float4*>(out + (size_t)r * ED + lane * 4) =
        *reinterpret_cast<const float4*>(e + (size_t)bc * ED + lane * 4);
}

extern "C" void kernel_launch(void* const* d_in, const int* in_sizes, int n_in,
                              void* d_out, int out_size, void* d_ws, size_t ws_size,
                              hipStream_t stream) {
    const float* z = (const float*)d_in[0];
    const float* e = (const float*)d_in[1];
    float* out   = (float*)d_out;
    float* e2np  = (float*)d_ws;                 // 8192 f32
    float* z2np  = e2np + NE;                    // 32768 f32
    float* wsmin = z2np + BS;                    // 32768 x 128 f32 = 16 MB

    hipLaunchKernelGGL(sq_np_kernel, dim3(NE / 32), dim3(256), 0, stream, e, e2np);
    hipLaunchKernelGGL(sq_np_kernel, dim3(BS / 32), dim3(256), 0, stream, z, z2np);
    hipLaunchKernelGGL(vq_pass1, dim3(256 * 64), dim3(256), 0, stream, z, e, e2np, wsmin);
    hipLaunchKernelGGL(vq_pass2, dim3(BS / 4), dim3(256), 0, stream, z, e, z2np, e2np, wsmin, out);
}

// Round 4
// 800.402 us; speedup vs baseline: 2.9447x; 1.8089x over previous
//
#include <hip/hip_runtime.h>

constexpr int NE = 8192;
constexpr int ED = 256;
constexpr int BS = 32768;
constexpr float DELTA = 4e-4f;   // worst-case |d_bf16 - d_np| bound (row-shift removed) x safety

typedef short bf16x8 __attribute__((ext_vector_type(8)));
typedef float f32x4 __attribute__((ext_vector_type(4)));

__device__ __forceinline__ short f2bf(float f) {            // RNE f32 -> bf16
    unsigned u = __float_as_uint(f);
    u = u + 0x7FFFu + ((u >> 16) & 1u);
    return (short)(u >> 16);
}

// ---------- np-exact pairwise ||row||^2 (verified bit-exact vs np.sum in R2) ----------
__global__ void sq_np_kernel(const float* __restrict__ a, float* __restrict__ out) {
    int gtid = blockIdx.x * blockDim.x + threadIdx.x;
    int wave = gtid >> 6;
    int lane = threadIdx.x & 63;
    int sub  = lane & 7;
    int row  = wave * 8 + (lane >> 3);
    const float* p = a + (size_t)row * ED;
    float b0 = 0.f, b1 = 0.f;
#pragma unroll
    for (int t = 0; t < 16; ++t) { float v = p[8 * t + sub];       b0 = __fadd_rn(b0, __fmul_rn(v, v)); }
#pragma unroll
    for (int t = 0; t < 16; ++t) { float v = p[128 + 8 * t + sub]; b1 = __fadd_rn(b1, __fmul_rn(v, v)); }
    b0 = __fadd_rn(b0, __shfl_xor(b0, 1));
    b0 = __fadd_rn(b0, __shfl_xor(b0, 2));
    b0 = __fadd_rn(b0, __shfl_xor(b0, 4));
    b1 = __fadd_rn(b1, __shfl_xor(b1, 1));
    b1 = __fadd_rn(b1, __shfl_xor(b1, 2));
    b1 = __fadd_rn(b1, __shfl_xor(b1, 4));
    if (sub == 0) out[row] = __fadd_rn(b0, b1);
}

// ---------- pass 1: bf16 MFMA GEMM, per-(row, 64-col-chunk) min of d' = e2 - 2*dot ----------
__global__ __launch_bounds__(256) void vq_pass1(
        const float* __restrict__ z, const float* __restrict__ e,
        const float* __restrict__ e2, float* __restrict__ wsmin) {
    __shared__ __align__(16) char smem[32768];
    char* As = smem;
    char* Bs = smem + 16384;

    const int tid  = threadIdx.x;
    const int bm   = blockIdx.x & 255;   // m fastest: consecutive blocks share B-tile (L2)
    const int bn   = blockIdx.x >> 8;
    const int row0 = bm * 128;
    const int col0 = bn * 128;

    const int wid  = tid >> 6, lane = tid & 63;
    const int wr   = (wid >> 1) * 64, wc = (wid & 1) * 64;
    const int lr   = lane & 15;
    const int lk   = lane >> 4;
    const int sw   = (lr & 7) << 4;

    f32x4 acc[4][4];
#pragma unroll
    for (int i = 0; i < 4; ++i)
#pragma unroll
        for (int j = 0; j < 4; ++j) acc[i][j] = (f32x4){0.f, 0.f, 0.f, 0.f};

    for (int kstep = 0; kstep < 4; ++kstep) {
        const int k0 = kstep * 64;
        if (kstep) __syncthreads();
#pragma unroll
        for (int it = 0; it < 4; ++it) {
            int idx = tid + it * 256;
            int m = idx >> 3, ku = idx & 7;
            const float4* sa = reinterpret_cast<const float4*>(
                z + (size_t)(row0 + m) * ED + k0 + ku * 8);
            float4 a0 = sa[0], a1 = sa[1];
            bf16x8 ha;
            ha[0] = f2bf(a0.x); ha[1] = f2bf(a0.y); ha[2] = f2bf(a0.z); ha[3] = f2bf(a0.w);
            ha[4] = f2bf(a1.x); ha[5] = f2bf(a1.y); ha[6] = f2bf(a1.z); ha[7] = f2bf(a1.w);
            *reinterpret_cast<bf16x8*>(As + m * 128 + ((ku * 16) ^ ((m & 7) << 4))) = ha;
            const float4* sb = reinterpret_cast<const float4*>(
                e + (size_t)(col0 + m) * ED + k0 + ku * 8);
            float4 b0 = sb[0], b1 = sb[1];
            bf16x8 hb;
            hb[0] = f2bf(b0.x); hb[1] = f2bf(b0.y); hb[2] = f2bf(b0.z); hb[3] = f2bf(b0.w);
            hb[4] = f2bf(b1.x); hb[5] = f2bf(b1.y); hb[6] = f2bf(b1.z); hb[7] = f2bf(b1.w);
            *reinterpret_cast<bf16x8*>(Bs + m * 128 + ((ku * 16) ^ ((m & 7) << 4))) = hb;
        }
        __syncthreads();
#pragma unroll
        for (int ks = 0; ks < 2; ++ks) {
            bf16x8 af[4], bg[4];
#pragma unroll
            for (int i = 0; i < 4; ++i) {
                int mrow = wr + i * 16 + lr;
                af[i] = *reinterpret_cast<const bf16x8*>(
                    As + mrow * 128 + (((ks * 4 + lk) * 16) ^ sw));
                int ncol = wc + i * 16 + lr;
                bg[i] = *reinterpret_cast<const bf16x8*>(
                    Bs + ncol * 128 + (((ks * 4 + lk) * 16) ^ sw));
            }
#pragma unroll
            for (int i = 0; i < 4; ++i)
#pragma unroll
                for (int j = 0; j < 4; ++j)
                    acc[i][j] = __builtin_amdgcn_mfma_f32_16x16x32_bf16(
                        af[i], bg[j], acc[i][j], 0, 0, 0);
        }
    }

    float e2v[4];
#pragma unroll
    for (int j = 0; j < 4; ++j) e2v[j] = e2[col0 + wc + j * 16 + lr];
    const int chunk = (col0 + wc) >> 6;
#pragma unroll
    for (int i = 0; i < 4; ++i) {
#pragma unroll
        for (int q = 0; q < 4; ++q) {
            float m0 = fminf(fminf(e2v[0] - 2.f * acc[i][0][q],
                                   e2v[1] - 2.f * acc[i][1][q]),
                             fminf(e2v[2] - 2.f * acc[i][2][q],
                                   e2v[3] - 2.f * acc[i][3][q]));
#pragma unroll
            for (int off = 1; off < 16; off <<= 1)
                m0 = fminf(m0, __shfl_xor(m0, off));
            if (lr == 0) {
                int row = row0 + wr + i * 16 + lk * 4 + q;
                wsmin[(size_t)row * 128 + chunk] = m0;
            }
        }
    }
}

// ---------- pass 2: exact re-eval of ballot-selected chunks, 1 column/lane ----------
__global__ __launch_bounds__(256) void vq_pass2(
        const float* __restrict__ z, const float* __restrict__ e,
        const float* __restrict__ z2, const float* __restrict__ e2,
        const float* __restrict__ wsmin, float* __restrict__ out) {
    __shared__ __align__(16) float zrow[4][ED];
    const int wid = threadIdx.x >> 6, lane = threadIdx.x & 63;
    const int r = blockIdx.x * 4 + wid;

    *reinterpret_cast<float4*>(&zrow[wid][lane * 4]) =
        *reinterpret_cast<const float4*>(z + (size_t)r * ED + lane * 4);
    __syncthreads();

    const float z2r = z2[r];
    float ca = wsmin[(size_t)r * 128 + lane];
    float cb = wsmin[(size_t)r * 128 + 64 + lane];
    float rmn = fminf(ca, cb);
#pragma unroll
    for (int off = 1; off < 64; off <<= 1) rmn = fminf(rmn, __shfl_xor(rmn, off));
    const float thr = rmn + DELTA;

    unsigned long long m0 = __ballot(ca <= thr);
    unsigned long long m1 = __ballot(cb <= thr);

    float bd = 3.4e38f;
    int   bc = NE;
#pragma unroll
    for (int half = 0; half < 2; ++half) {
        unsigned long long msk = half ? m1 : m0;
        while (msk) {
            int ch = __builtin_ctzll(msk) + half * 64;
            msk &= msk - 1;
            const int col = ch * 64 + lane;             // one column per lane
            const float* ec = e + (size_t)col * ED;
            // np-einsum exact: 4 sequential lane-accumulators, in-lane (4x ILP)
            float a0 = 0.f, a1 = 0.f, a2 = 0.f, a3 = 0.f;
#pragma unroll 8
            for (int t = 0; t < 64; ++t) {
                float4 ev = *reinterpret_cast<const float4*>(ec + 4 * t);
                float4 zv = *reinterpret_cast<const float4*>(&zrow[wid][4 * t]);
                a0 = __fadd_rn(a0, __fmul_rn(zv.x, ev.x));
                a1 = __fadd_rn(a1, __fmul_rn(zv.y, ev.y));
                a2 = __fadd_rn(a2, __fmul_rn(zv.z, ev.z));
                a3 = __fadd_rn(a3, __fmul_rn(zv.w, ev.w));
            }
            float s = __fadd_rn(__fadd_rn(a0, a1), __fadd_rn(a2, a3));
            float d = __fsub_rn(__fadd_rn(z2r, e2[col]), __fmul_rn(2.0f, s));
            if (d < bd || (d == bd && col < bc)) { bd = d; bc = col; }
        }
    }
#pragma unroll
    for (int off = 1; off < 64; off <<= 1) {
        float od = __shfl_xor(bd, off);
        int   oc = __shfl_xor(bc, off);
        if (od < bd || (od == bd && oc < bc)) { bd = od; bc = oc; }
    }
    if (lane == 0) out[(size_t)BS * ED + r] = (float)bc;
    *reinterpret_cast<float4*>(out + (size_t)r * ED + lane * 4) =
        *reinterpret_cast<const float4*>(e + (size_t)bc * ED + lane * 4);
}

extern "C" void kernel_launch(void* const* d_in, const int* in_sizes, int n_in,
                              void* d_out, int out_size, void* d_ws, size_t ws_size,
                              hipStream_t stream) {
    const float* z = (const float*)d_in[0];
    const float* e = (const float*)d_in[1];
    float* out   = (float*)d_out;
    float* e2np  = (float*)d_ws;                 // 8192 f32
    float* z2np  = e2np + NE;                    // 32768 f32
    float* wsmin = z2np + BS;                    // 32768 x 128 f32 = 16 MB

    hipLaunchKernelGGL(sq_np_kernel, dim3(NE / 32), dim3(256), 0, stream, e, e2np);
    hipLaunchKernelGGL(sq_np_kernel, dim3(BS / 32), dim3(256), 0, stream, z, z2np);
    hipLaunchKernelGGL(vq_pass1, dim3(256 * 64), dim3(256), 0, stream, z, e, e2np, wsmin);
    hipLaunchKernelGGL(vq_pass2, dim3(BS / 4), dim3(256), 0, stream, z, e, z2np, e2np, wsmin, out);
}

// Round 5
// 569.833 us; speedup vs baseline: 4.1361x; 1.4046x over previous
//
#include <hip/hip_runtime.h>

constexpr int NE = 8192;
constexpr int ED = 256;
constexpr int BS = 32768;
constexpr float DELTA = 4e-4f;   // >> 2*(bf16-MFMA err ~6e-6 + np-grid quantization ~3e-5)

typedef short bf16x8 __attribute__((ext_vector_type(8)));
typedef float f32x4 __attribute__((ext_vector_type(4)));

__device__ __forceinline__ short f2bf(float f) {            // RNE f32 -> bf16
    unsigned u = __float_as_uint(f);
    u = u + 0x7FFFu + ((u >> 16) & 1u);
    return (short)(u >> 16);
}
__device__ __forceinline__ unsigned bf16_rd(float x) {      // round toward -inf -> bf16 bits
    unsigned u = __float_as_uint(x);
    unsigned h = u >> 16;
    if ((u & 0x80000000u) && (u & 0xFFFFu)) ++h;            // negative: truncation was upward
    return h;
}

// ---------- np-exact pairwise ||row||^2 (verified bit-exact vs np.sum in R2) ----------
__global__ void sq_np_kernel(const float* __restrict__ a, float* __restrict__ out) {
    int gtid = blockIdx.x * blockDim.x + threadIdx.x;
    int wave = gtid >> 6;
    int lane = threadIdx.x & 63;
    int sub  = lane & 7;
    int row  = wave * 8 + (lane >> 3);
    const float* p = a + (size_t)row * ED;
    float b0 = 0.f, b1 = 0.f;
#pragma unroll
    for (int t = 0; t < 16; ++t) { float v = p[8 * t + sub];       b0 = __fadd_rn(b0, __fmul_rn(v, v)); }
#pragma unroll
    for (int t = 0; t < 16; ++t) { float v = p[128 + 8 * t + sub]; b1 = __fadd_rn(b1, __fmul_rn(v, v)); }
    b0 = __fadd_rn(b0, __shfl_xor(b0, 1));
    b0 = __fadd_rn(b0, __shfl_xor(b0, 2));
    b0 = __fadd_rn(b0, __shfl_xor(b0, 4));
    b1 = __fadd_rn(b1, __shfl_xor(b1, 1));
    b1 = __fadd_rn(b1, __shfl_xor(b1, 2));
    b1 = __fadd_rn(b1, __shfl_xor(b1, 4));
    if (sub == 0) out[row] = __fadd_rn(b0, b1);
}

// ---------- pass 1: bf16 MFMA GEMM; per-(row, 128-col chunk) {min, argmin, 2nd-min} ----------
__global__ __launch_bounds__(256) void vq_pass1(
        const float* __restrict__ z, const float* __restrict__ e,
        const float* __restrict__ e2, uint2* __restrict__ wsp) {
    __shared__ __align__(16) char smem[32768];
    char* As = smem;
    char* Bs = smem + 16384;

    const int tid  = threadIdx.x;
    const int bm   = blockIdx.x & 255;   // m fastest: consecutive blocks share B-tile (L2)
    const int bn   = blockIdx.x >> 8;    // bn == 128-col chunk id
    const int row0 = bm * 128;
    const int col0 = bn * 128;

    const int wid  = tid >> 6, lane = tid & 63;
    const int wr   = (wid >> 1) * 64, wc = (wid & 1) * 64;
    const int lr   = lane & 15;
    const int lk   = lane >> 4;
    const int sw   = (lr & 7) << 4;

    f32x4 acc[4][4];
#pragma unroll
    for (int i = 0; i < 4; ++i)
#pragma unroll
        for (int j = 0; j < 4; ++j) acc[i][j] = (f32x4){0.f, 0.f, 0.f, 0.f};

    for (int kstep = 0; kstep < 4; ++kstep) {
        const int k0 = kstep * 64;
        if (kstep) __syncthreads();
#pragma unroll
        for (int it = 0; it < 4; ++it) {
            int idx = tid + it * 256;
            int m = idx >> 3, ku = idx & 7;
            const float4* sa = reinterpret_cast<const float4*>(
                z + (size_t)(row0 + m) * ED + k0 + ku * 8);
            float4 a0 = sa[0], a1 = sa[1];
            bf16x8 ha;
            ha[0] = f2bf(a0.x); ha[1] = f2bf(a0.y); ha[2] = f2bf(a0.z); ha[3] = f2bf(a0.w);
            ha[4] = f2bf(a1.x); ha[5] = f2bf(a1.y); ha[6] = f2bf(a1.z); ha[7] = f2bf(a1.w);
            *reinterpret_cast<bf16x8*>(As + m * 128 + ((ku * 16) ^ ((m & 7) << 4))) = ha;
            const float4* sb = reinterpret_cast<const float4*>(
                e + (size_t)(col0 + m) * ED + k0 + ku * 8);
            float4 b0 = sb[0], b1 = sb[1];
            bf16x8 hb;
            hb[0] = f2bf(b0.x); hb[1] = f2bf(b0.y); hb[2] = f2bf(b0.z); hb[3] = f2bf(b0.w);
            hb[4] = f2bf(b1.x); hb[5] = f2bf(b1.y); hb[6] = f2bf(b1.z); hb[7] = f2bf(b1.w);
            *reinterpret_cast<bf16x8*>(Bs + m * 128 + ((ku * 16) ^ ((m & 7) << 4))) = hb;
        }
        __syncthreads();
#pragma unroll
        for (int ks = 0; ks < 2; ++ks) {
            bf16x8 af[4], bg[4];
#pragma unroll
            for (int i = 0; i < 4; ++i) {
                int mrow = wr + i * 16 + lr;
                af[i] = *reinterpret_cast<const bf16x8*>(
                    As + mrow * 128 + (((ks * 4 + lk) * 16) ^ sw));
                int ncol = wc + i * 16 + lr;
                bg[i] = *reinterpret_cast<const bf16x8*>(
                    Bs + ncol * 128 + (((ks * 4 + lk) * 16) ^ sw));
            }
#pragma unroll
            for (int i = 0; i < 4; ++i)
#pragma unroll
                for (int j = 0; j < 4; ++j)
                    acc[i][j] = __builtin_amdgcn_mfma_f32_16x16x32_bf16(
                        af[i], bg[j], acc[i][j], 0, 0, 0);
        }
    }

    // -------- epilogue: per (row, wave-half) top-2 over 64 cols, then cross-half merge --------
    float e2v[4];
#pragma unroll
    for (int j = 0; j < 4; ++j) e2v[j] = e2[col0 + wc + j * 16 + lr];

    __syncthreads();                       // As/Bs dead; reuse smem for merge arrays
    float* lm1 = reinterpret_cast<float*>(smem);            // [2][128]
    float* lm2 = lm1 + 256;                                 // [2][128]
    int*   lix = reinterpret_cast<int*>(lm2 + 256);         // [2][128]

#pragma unroll
    for (int i = 0; i < 4; ++i) {
#pragma unroll
        for (int q = 0; q < 4; ++q) {
            float m1 = 3.4e38f, m2 = 3.4e38f;
            int   i1 = 0;
#pragma unroll
            for (int j = 0; j < 4; ++j) {
                float v = e2v[j] - 2.f * acc[i][j][q];
                int   c = wc + j * 16 + lr;               // col within 128-chunk
                if (v < m1 || (v == m1 && c < i1)) { m2 = m1; m1 = v; i1 = c; }
                else m2 = fminf(m2, v);
            }
#pragma unroll
            for (int off = 1; off < 16; off <<= 1) {
                float om1 = __shfl_xor(m1, off);
                int   oi1 = __shfl_xor(i1, off);
                float om2 = __shfl_xor(m2, off);
                if (om1 < m1 || (om1 == m1 && oi1 < i1)) {
                    m2 = fminf(m1, om2); m1 = om1; i1 = oi1;
                } else {
                    m2 = fminf(m2, om1);
                }
            }
            if (lr == 0) {
                int rloc = wr + i * 16 + lk * 4 + q;      // 0..127
                int half = wid & 1;
                lm1[half * 128 + rloc] = m1;
                lm2[half * 128 + rloc] = m2;
                lix[half * 128 + rloc] = i1;
            }
        }
    }
    __syncthreads();
    if (tid < 128) {
        float m1a = lm1[tid],       m2a = lm2[tid];       int ia = lix[tid];
        float m1b = lm1[128 + tid], m2b = lm2[128 + tid]; int ib = lix[128 + tid];
        float M1, M2; int I1;
        if (m1a < m1b || (m1a == m1b && ia < ib)) { M1 = m1a; I1 = ia; M2 = fminf(m2a, m1b); }
        else                                      { M1 = m1b; I1 = ib; M2 = fminf(m2b, m1a); }
        wsp[(size_t)(row0 + tid) * 64 + bn] =
            make_uint2(__float_as_uint(M1), (bf16_rd(M2) << 16) | (unsigned)I1);
    }
}

// ---------- pass 2: candidate-column exact np re-eval + argmin + gather ----------
__global__ __launch_bounds__(256) void vq_pass2(
        const float* __restrict__ z, const float* __restrict__ e,
        const float* __restrict__ z2, const float* __restrict__ e2,
        const uint2* __restrict__ wsp, float* __restrict__ out) {
    __shared__ __align__(16) float zrow[4][ED];
    const int wid = threadIdx.x >> 6, lane = threadIdx.x & 63;
    const int r = blockIdx.x * 4 + wid;

    *reinterpret_cast<float4*>(&zrow[wid][lane * 4]) =
        *reinterpret_cast<const float4*>(z + (size_t)r * ED + lane * 4);
    __syncthreads();

    const float z2r = z2[r];
    uint2 p = wsp[(size_t)r * 64 + lane];                 // one 128-chunk per lane
    float m1 = __uint_as_float(p.x);
    int   i8 = (int)(p.y & 0xFFu);
    float m2 = __uint_as_float(p.y & 0xFFFF0000u);        // conservative (<= true m2)

    float rmn = m1;
#pragma unroll
    for (int off = 1; off < 64; off <<= 1) rmn = fminf(rmn, __shfl_xor(rmn, off));
    const float thr = rmn + DELTA;

    const bool cF = (m2 <= thr);                          // chunk needs full eval
    const bool cS = (m1 <= thr) && !cF;                   // only argmin col can qualify
    unsigned long long bS = __ballot(cS);
    unsigned long long bF = __ballot(cF);

    float bd = 3.4e38f;
    int   bc = NE;

    // ---- single-column candidates: batch into lanes, eval one col per lane ----
    int myCol = -1;
    int cnt = 0;
    unsigned long long m = bS;
    while (true) {
        bool flush = (m == 0) || (cnt == 64);
        if (flush) {
            if (cnt > 0) {
                int ecol = (myCol >= 0) ? myCol : 0;
                const float* ec = e + (size_t)ecol * ED;
                float a0 = 0.f, a1 = 0.f, a2 = 0.f, a3 = 0.f;
#pragma unroll 8
                for (int t = 0; t < 64; ++t) {
                    float4 ev = *reinterpret_cast<const float4*>(ec + 4 * t);
                    float4 zv = *reinterpret_cast<const float4*>(&zrow[wid][4 * t]);
                    a0 = __fadd_rn(a0, __fmul_rn(zv.x, ev.x));
                    a1 = __fadd_rn(a1, __fmul_rn(zv.y, ev.y));
                    a2 = __fadd_rn(a2, __fmul_rn(zv.z, ev.z));
                    a3 = __fadd_rn(a3, __fmul_rn(zv.w, ev.w));
                }
                float s = __fadd_rn(__fadd_rn(a0, a1), __fadd_rn(a2, a3));
                float d = __fsub_rn(__fadd_rn(z2r, e2[ecol]), __fmul_rn(2.0f, s));
                if (myCol >= 0 && (d < bd || (d == bd && ecol < bc))) { bd = d; bc = ecol; }
                myCol = -1; cnt = 0;
            }
            if (m == 0) break;
        }
        int ch = __builtin_ctzll(m); m &= m - 1;
        int col = ch * 128 + __shfl(i8, ch);
        if (lane == cnt) myCol = col;
        ++cnt;
    }

    // ---- full-chunk candidates (rare; covers exact d'-ties automatically) ----
    m = bF;
    while (m) {
        int ch = __builtin_ctzll(m); m &= m - 1;
#pragma unroll
        for (int hh = 0; hh < 2; ++hh) {
            int col = ch * 128 + hh * 64 + lane;
            const float* ec = e + (size_t)col * ED;
            float a0 = 0.f, a1 = 0.f, a2 = 0.f, a3 = 0.f;
#pragma unroll 8
            for (int t = 0; t < 64; ++t) {
                float4 ev = *reinterpret_cast<const float4*>(ec + 4 * t);
                float4 zv = *reinterpret_cast<const float4*>(&zrow[wid][4 * t]);
                a0 = __fadd_rn(a0, __fmul_rn(zv.x, ev.x));
                a1 = __fadd_rn(a1, __fmul_rn(zv.y, ev.y));
                a2 = __fadd_rn(a2, __fmul_rn(zv.z, ev.z));
                a3 = __fadd_rn(a3, __fmul_rn(zv.w, ev.w));
            }
            float s = __fadd_rn(__fadd_rn(a0, a1), __fadd_rn(a2, a3));
            float d = __fsub_rn(__fadd_rn(z2r, e2[col]), __fmul_rn(2.0f, s));
            if (d < bd || (d == bd && col < bc)) { bd = d; bc = col; }
        }
    }

    // ---- lexicographic (d, col) min across the wave ----
#pragma unroll
    for (int off = 1; off < 64; off <<= 1) {
        float od = __shfl_xor(bd, off);
        int   oc = __shfl_xor(bc, off);
        if (od < bd || (od == bd && oc < bc)) { bd = od; bc = oc; }
    }
    if (lane == 0) out[(size_t)BS * ED + r] = (float)bc;
    *reinterpret_cast<float4*>(out + (size_t)r * ED + lane * 4) =
        *reinterpret_cast<const float4*>(e + (size_t)bc * ED + lane * 4);
}

extern "C" void kernel_launch(void* const* d_in, const int* in_sizes, int n_in,
                              void* d_out, int out_size, void* d_ws, size_t ws_size,
                              hipStream_t stream) {
    const float* z = (const float*)d_in[0];
    const float* e = (const float*)d_in[1];
    float* out   = (float*)d_out;
    float* e2np  = (float*)d_ws;                     // 8192 f32
    float* z2np  = e2np + NE;                        // 32768 f32
    uint2* wsp   = (uint2*)(z2np + BS);              // 32768 x 64 x 8B = 16 MB

    hipLaunchKernelGGL(sq_np_kernel, dim3(NE / 32), dim3(256), 0, stream, e, e2np);
    hipLaunchKernelGGL(sq_np_kernel, dim3(BS / 32), dim3(256), 0, stream, z, z2np);
    hipLaunchKernelGGL(vq_pass1, dim3(256 * 64), dim3(256), 0, stream, z, e, e2np, wsp);
    hipLaunchKernelGGL(vq_pass2, dim3(BS / 4), dim3(256), 0, stream, z, e, z2np, e2np, wsp, out);
}